// Round 1
// baseline (771.179 us; speedup 1.0000x reference)
//
#include <hip/hip_runtime.h>
#include <hip/hip_bf16.h>

typedef __attribute__((ext_vector_type(8))) short short8;
typedef __attribute__((ext_vector_type(4))) float f32x4;

#define B_N 4
#define SEQ 2048
#define NH 16
#define HDIM 128
#define QT 64
#define KT 64

static __device__ __forceinline__ unsigned short f2bf(float f) {
  union { __hip_bfloat16 h; unsigned short u; } cv;
  cv.h = __float2bfloat16(f);
  return cv.u;
}
static __device__ __forceinline__ unsigned int pack2(float a, float b) {
  return (unsigned int)f2bf(a) | ((unsigned int)f2bf(b) << 16);
}

__global__ __launch_bounds__(256)
void fattn_kernel(const float* __restrict__ Qg, const float* __restrict__ Kg,
                  const float* __restrict__ Vg, const float* __restrict__ Sg,
                  float* __restrict__ Og)
{
  // K tile: [k][d] bf16 row-major, XOR-swizzled. 64*128*2 = 16 KiB
  __shared__ char Ks[KT * HDIM * 2];
  // V tile transposed: [d][k] bf16, XOR-swizzled. 128*64*2 = 16 KiB
  __shared__ char Vs[HDIM * KT * 2];
  // per-wave P tile: [16][64] bf16, XOR-swizzled. 4 * 2 KiB
  __shared__ char Ps[4][16 * KT * 2];

  const int tid  = threadIdx.x;
  const int wv   = tid >> 6;
  const int lane = tid & 63;
  const int l15  = lane & 15;
  const int lg   = lane >> 4;

  const int q0 = blockIdx.x * QT;
  const int bh = blockIdx.y;
  const int b  = bh >> 4;          // H = 16
  const int h  = bh & (NH - 1);

  const float slope = Sg[h];
  const float scale = 0.08838834764831845f;   // 1/sqrt(128)

  const long strideS = (long)NH * HDIM;       // floats per seq position

  // ---- Q fragments (A-operand: row = l15, k = lg*8+j), pre-scaled ----
  const int gq = q0 + wv * 16 + l15;
  const float* qp = Qg + ((long)b * SEQ + gq) * strideS + (long)h * HDIM;
  short8 qf[4];
#pragma unroll
  for (int c = 0; c < 4; ++c) {
    const float* p = qp + c * 32 + lg * 8;
    float4 x = *(const float4*)p;
    float4 y = *(const float4*)(p + 4);
    short8 f;
    f[0]=(short)f2bf(x.x*scale); f[1]=(short)f2bf(x.y*scale);
    f[2]=(short)f2bf(x.z*scale); f[3]=(short)f2bf(x.w*scale);
    f[4]=(short)f2bf(y.x*scale); f[5]=(short)f2bf(y.y*scale);
    f[6]=(short)f2bf(y.z*scale); f[7]=(short)f2bf(y.w*scale);
    qf[c] = f;
  }

  float mrow[4], lrow[4];
  f32x4 acc[8];
#pragma unroll
  for (int r = 0; r < 4; ++r) { mrow[r] = -1e30f; lrow[r] = 0.f; }
#pragma unroll
  for (int d = 0; d < 8; ++d) acc[d] = (f32x4){0.f, 0.f, 0.f, 0.f};

  const float* kb = Kg + (long)b * SEQ * strideS + (long)h * HDIM;
  const float* vb = Vg + (long)b * SEQ * strideS + (long)h * HDIM;

  const float qpos0 = (float)(q0 + wv * 16 + lg * 4);   // q pos of reg r=0

  const int ntile = q0 / KT + 1;   // causal: skip tiles fully above diagonal
  for (int t = 0; t < ntile; ++t) {
    const int k0 = t * KT;
    __syncthreads();

    // ---- stage K tile (coalesced float4, bf16 pack, swizzled store) ----
#pragma unroll
    for (int i = 0; i < 8; ++i) {
      int f4 = tid + i * 256;           // 0..2047
      int row = f4 >> 5, c4 = f4 & 31;
      float4 x = *(const float4*)(kb + (long)(k0 + row) * strideS + c4 * 4);
      uint2 w; w.x = pack2(x.x, x.y); w.y = pack2(x.z, x.w);
      int byt = (row * 256 + c4 * 8) ^ ((row & 7) << 4);
      *(uint2*)(Ks + byt) = w;
    }
    // ---- stage V^T tile: 4x4 blocks, 2 per thread ----
#pragma unroll
    for (int i = 0; i < 2; ++i) {
      int blk = tid + i * 256;           // 0..511
      int d4 = blk & 31, k4 = blk >> 5;  // d-group 0..31, k-group 0..15
      const float* vp = vb + (long)(k0 + k4 * 4) * strideS + d4 * 4;
      float4 r0 = *(const float4*)vp;
      float4 r1 = *(const float4*)(vp + strideS);
      float4 r2 = *(const float4*)(vp + 2 * strideS);
      float4 r3 = *(const float4*)(vp + 3 * strideS);
      const float c0[4] = {r0.x, r0.y, r0.z, r0.w};
      const float c1[4] = {r1.x, r1.y, r1.z, r1.w};
      const float c2[4] = {r2.x, r2.y, r2.z, r2.w};
      const float c3[4] = {r3.x, r3.y, r3.z, r3.w};
#pragma unroll
      for (int dd = 0; dd < 4; ++dd) {
        int d = d4 * 4 + dd;
        uint2 w; w.x = pack2(c0[dd], c1[dd]); w.y = pack2(c2[dd], c3[dd]);
        int byt = (d * (KT * 2) + k4 * 8) ^ ((d & 7) << 4);
        *(uint2*)(Vs + byt) = w;
      }
    }
    __syncthreads();

    // ---- S = (Q*scale) K^T  (per wave: 16 q-rows x 64 k-cols) ----
    f32x4 s[4];
#pragma unroll
    for (int sub = 0; sub < 4; ++sub) {
      s[sub] = (f32x4){0.f, 0.f, 0.f, 0.f};
      int krow = sub * 16 + l15;
      int rowbase = krow * 256;
      int swz = (krow & 7) << 4;
#pragma unroll
      for (int c = 0; c < 4; ++c) {
        int byt = (rowbase + c * 64 + lg * 16) ^ swz;
        short8 kf = *(const short8*)(Ks + byt);
        s[sub] = __builtin_amdgcn_mfma_f32_16x16x32_bf16(qf[c], kf, s[sub], 0, 0, 0);
      }
    }

    // ---- ALiBi + causal mask + online softmax ----
    float tmax[4] = {-1e30f, -1e30f, -1e30f, -1e30f};
#pragma unroll
    for (int sub = 0; sub < 4; ++sub) {
      float kpos = (float)(k0 + sub * 16 + l15);
#pragma unroll
      for (int r = 0; r < 4; ++r) {
        float dlt = kpos - (qpos0 + (float)r);
        float v = s[sub][r] + slope * dlt;
        v = (dlt > 0.f) ? -1e30f : v;
        s[sub][r] = v;
        tmax[r] = fmaxf(tmax[r], v);
      }
    }
#pragma unroll
    for (int off = 1; off < 16; off <<= 1) {
#pragma unroll
      for (int r = 0; r < 4; ++r)
        tmax[r] = fmaxf(tmax[r], __shfl_xor(tmax[r], off, 64));
    }
    float alpha[4], psum[4];
#pragma unroll
    for (int r = 0; r < 4; ++r) {
      float M = fmaxf(mrow[r], tmax[r]);
      alpha[r] = __expf(mrow[r] - M);
      mrow[r] = M;
      psum[r] = 0.f;
    }
#pragma unroll
    for (int sub = 0; sub < 4; ++sub) {
#pragma unroll
      for (int r = 0; r < 4; ++r) {
        float p = __expf(s[sub][r] - mrow[r]);
        s[sub][r] = p;
        psum[r] += p;
      }
    }
#pragma unroll
    for (int off = 1; off < 16; off <<= 1) {
#pragma unroll
      for (int r = 0; r < 4; ++r)
        psum[r] += __shfl_xor(psum[r], off, 64);
    }
#pragma unroll
    for (int r = 0; r < 4; ++r)
      lrow[r] = lrow[r] * alpha[r] + psum[r];
#pragma unroll
    for (int d = 0; d < 8; ++d)
#pragma unroll
      for (int r = 0; r < 4; ++r)
        acc[d][r] *= alpha[r];

    // ---- P -> per-wave LDS tile (re-fragment for PV A-operand) ----
    char* pw = Ps[wv];
#pragma unroll
    for (int sub = 0; sub < 4; ++sub) {
#pragma unroll
      for (int r = 0; r < 4; ++r) {
        int row = lg * 4 + r;
        int byt = (row * 128 + (sub * 16 + l15) * 2) ^ ((row & 7) << 4);
        *(unsigned short*)(pw + byt) = f2bf(s[sub][r]);
      }
    }
    short8 pf[2];
#pragma unroll
    for (int kc = 0; kc < 2; ++kc) {
      int byt = (l15 * 128 + kc * 64 + lg * 16) ^ ((l15 & 7) << 4);
      pf[kc] = *(const short8*)(pw + byt);
    }

    // ---- O += P V ----
#pragma unroll
    for (int dsb = 0; dsb < 8; ++dsb) {
      int d = dsb * 16 + l15;
      int rowbase = d * (KT * 2);
      int swz = (d & 7) << 4;
#pragma unroll
      for (int kc = 0; kc < 2; ++kc) {
        int byt = (rowbase + kc * 64 + lg * 16) ^ swz;
        short8 vf = *(const short8*)(Vs + byt);
        acc[dsb] = __builtin_amdgcn_mfma_f32_16x16x32_bf16(pf[kc], vf, acc[dsb], 0, 0, 0);
      }
    }
  }

  // ---- epilogue: O / l ----
  float inv[4];
#pragma unroll
  for (int r = 0; r < 4; ++r) inv[r] = 1.0f / lrow[r];
  float* op = Og + ((long)b * SEQ + q0 + wv * 16) * strideS + (long)h * HDIM;
#pragma unroll
  for (int dsb = 0; dsb < 8; ++dsb) {
#pragma unroll
    for (int r = 0; r < 4; ++r) {
      int row = lg * 4 + r;
      op[(long)row * strideS + dsb * 16 + l15] = acc[dsb][r] * inv[r];
    }
  }
}

extern "C" void kernel_launch(void* const* d_in, const int* in_sizes, int n_in,
                              void* d_out, int out_size, void* d_ws, size_t ws_size,
                              hipStream_t stream) {
  const float* Q = (const float*)d_in[0];
  const float* K = (const float*)d_in[1];
  const float* V = (const float*)d_in[2];
  const float* S = (const float*)d_in[3];
  float* O = (float*)d_out;
  dim3 grid(SEQ / QT, B_N * NH);
  dim3 block(256);
  fattn_kernel<<<grid, block, 0, stream>>>(Q, K, V, S, O);
}

// Round 2
// 265.804 us; speedup vs baseline: 2.9013x; 2.9013x over previous
//
#include <hip/hip_runtime.h>
#include <hip/hip_bf16.h>

typedef __attribute__((ext_vector_type(8))) short short8;
typedef __attribute__((ext_vector_type(16))) float f32x16;

#define B_N 4
#define SEQ 2048
#define NH 16
#define HDIM 128
#define QT 128      // q rows per block
#define QW 32       // q rows per wave
#define KT 64       // k tile

static __device__ __forceinline__ unsigned short f2bf(float f) {
  union { __hip_bfloat16 h; unsigned short u; } cv;
  cv.h = __float2bfloat16(f);
  return cv.u;
}
static __device__ __forceinline__ unsigned int pack2(float a, float b) {
  return (unsigned int)f2bf(a) | ((unsigned int)f2bf(b) << 16);
}
static __device__ __forceinline__ unsigned int cvtpk(float lo, float hi) {
  unsigned int r;
  asm("v_cvt_pk_bf16_f32 %0, %1, %2" : "=v"(r) : "v"(lo), "v"(hi));
  return r;
}

__global__ __launch_bounds__(256, 2)
void fattn_kernel(const float* __restrict__ Qg, const float* __restrict__ Kg,
                  const float* __restrict__ Vg, const float* __restrict__ Sg,
                  float* __restrict__ Og)
{
  // K tile: [kpos][d] bf16, XOR-swizzled (row stride 256B). 16 KiB
  __shared__ __align__(16) char Ks[KT * HDIM * 2];
  // V tile transposed: [d][kpos] bf16, XOR-swizzled (row stride 128B). 16 KiB
  __shared__ __align__(16) char Vs[HDIM * KT * 2];

  const int tid  = threadIdx.x;
  const int wv   = tid >> 6;
  const int lane = tid & 63;
  const int l31  = lane & 31;
  const int h    = lane >> 5;

  const int q0 = blockIdx.x * QT;
  const int bh = blockIdx.y;
  const int b  = bh >> 4;           // H = 16
  const int hh = bh & (NH - 1);

  const float slope = Sg[hh];
  const float scale = 0.08838834764831845f;   // 1/sqrt(128)
  const long strideS = (long)NH * HDIM;

  // ---- Q fragments: lane holds row q = q0w + l31, B-operand layout
  //      (col = l31, k = h*8 + j per 16-d chunk), pre-scaled ----
  const int q0w  = q0 + wv * QW;
  const int qrow = q0w + l31;
  const float* qp = Qg + ((long)b * SEQ + qrow) * strideS + (long)hh * HDIM;
  short8 qf[8];
#pragma unroll
  for (int c = 0; c < 8; ++c) {
    const float* p = qp + c * 16 + h * 8;
    float4 x = *(const float4*)p;
    float4 y = *(const float4*)(p + 4);
    short8 f;
    f[0]=(short)f2bf(x.x*scale); f[1]=(short)f2bf(x.y*scale);
    f[2]=(short)f2bf(x.z*scale); f[3]=(short)f2bf(x.w*scale);
    f[4]=(short)f2bf(y.x*scale); f[5]=(short)f2bf(y.y*scale);
    f[6]=(short)f2bf(y.z*scale); f[7]=(short)f2bf(y.w*scale);
    qf[c] = f;
  }

  float m_run = -1e30f, l_run = 0.f;
  f32x16 acc[4];
#pragma unroll
  for (int nb = 0; nb < 4; ++nb)
#pragma unroll
    for (int i = 0; i < 16; ++i) acc[nb][i] = 0.f;

  const float* kb = Kg + (long)b * SEQ * strideS + (long)hh * HDIM;
  const float* vb = Vg + (long)b * SEQ * strideS + (long)hh * HDIM;

  const float q_f = (float)qrow;
  const int myend = (q0w + QW - 1) / KT;   // last tile this wave needs
  const int ntile = q0 / KT + 2;           // tiles the block stages

  for (int t = 0; t < ntile; ++t) {
    const int k0 = t * KT;
    __syncthreads();

    // ---- stage K tile: fp32 -> bf16, swizzled ----
#pragma unroll
    for (int i = 0; i < 8; ++i) {
      int f4 = tid + i * 256;           // 0..2047
      int row = f4 >> 5, c4 = f4 & 31;
      float4 x = *(const float4*)(kb + (long)(k0 + row) * strideS + c4 * 4);
      uint2 w; w.x = pack2(x.x, x.y); w.y = pack2(x.z, x.w);
      int byt = (row * 256 + c4 * 8) ^ ((row & 7) << 4);
      *(uint2*)(Ks + byt) = w;
    }
    // ---- stage V^T tile: 4x4 transpose blocks ----
#pragma unroll
    for (int i = 0; i < 2; ++i) {
      int blk = tid + i * 256;           // 0..511
      int d4 = blk & 31, k4 = blk >> 5;
      const float* vp = vb + (long)(k0 + k4 * 4) * strideS + d4 * 4;
      float4 r0 = *(const float4*)vp;
      float4 r1 = *(const float4*)(vp + strideS);
      float4 r2 = *(const float4*)(vp + 2 * strideS);
      float4 r3 = *(const float4*)(vp + 3 * strideS);
      const float c0[4] = {r0.x, r0.y, r0.z, r0.w};
      const float c1[4] = {r1.x, r1.y, r1.z, r1.w};
      const float c2[4] = {r2.x, r2.y, r2.z, r2.w};
      const float c3[4] = {r3.x, r3.y, r3.z, r3.w};
#pragma unroll
      for (int dd = 0; dd < 4; ++dd) {
        int d = d4 * 4 + dd;
        uint2 w; w.x = pack2(c0[dd], c1[dd]); w.y = pack2(c2[dd], c3[dd]);
        int byt = (d * (KT * 2) + k4 * 8) ^ ((d & 7) << 4);
        *(uint2*)(Vs + byt) = w;
      }
    }
    __syncthreads();

    if (t <= myend) {
      // ---- S^T = K · Q^T : A = K rows (kpos), B = Q cols (q) ----
      f32x16 s0, s1;
#pragma unroll
      for (int i = 0; i < 16; ++i) { s0[i] = 0.f; s1[i] = 0.f; }
      const int swzk = (l31 & 7) << 4;
#pragma unroll
      for (int c = 0; c < 8; ++c) {
        int colb = c * 32 + h * 16;
        short8 ka = *(const short8*)(Ks + ((l31 * 256 + colb) ^ swzk));
        short8 kbf = *(const short8*)(Ks + (((l31 + 32) * 256 + colb) ^ swzk));
        s0 = __builtin_amdgcn_mfma_f32_32x32x16_bf16(ka, qf[c], s0, 0, 0, 0);
        s1 = __builtin_amdgcn_mfma_f32_32x32x16_bf16(kbf, qf[c], s1, 0, 0, 0);
      }

      // ---- ALiBi + causal + online softmax (lane-local row) ----
      float p[32];
      float pm = -1e30f;
#pragma unroll
      for (int i = 0; i < 16; ++i) {
        float kp0 = (float)(k0 + (i & 3) + 8 * (i >> 2) + 4 * h);
        float d0 = kp0 - q_f;
        float v0 = s0[i] + slope * d0;
        v0 = (d0 > 0.f) ? -1e30f : v0;
        p[i] = v0;
        float d1 = d0 + 32.f;
        float v1 = s1[i] + slope * d1;
        v1 = (d1 > 0.f) ? -1e30f : v1;
        p[16 + i] = v1;
        pm = fmaxf(pm, fmaxf(v0, v1));
      }
      pm = fmaxf(pm, __shfl_xor(pm, 32));

      if (!__all(pm <= m_run)) {
        float M = fmaxf(m_run, pm);
        float alpha = __expf(m_run - M);
        m_run = M;
#pragma unroll
        for (int i = 0; i < 16; ++i) {
          int qr = (i & 3) + 8 * (i >> 2) + 4 * h;
          float al = __shfl(alpha, qr, 64);
          acc[0][i] *= al; acc[1][i] *= al; acc[2][i] *= al; acc[3][i] *= al;
        }
        l_run *= alpha;
      }

      float ps = 0.f;
#pragma unroll
      for (int i = 0; i < 32; ++i) {
        float e = __expf(p[i] - m_run);
        p[i] = e;
        ps += e;
      }
      ps += __shfl_xor(ps, 32);
      l_run += ps;

      // ---- P (f32, S^T layout) -> PV A-fragments via cvt_pk + permlane32_swap ----
      short8 pa[4];
#pragma unroll
      for (int kc = 0; kc < 4; ++kc) {
        const int base = kc * 8;
        unsigned int a0 = cvtpk(p[base + 0], p[base + 1]);
        unsigned int b0 = cvtpk(p[base + 4], p[base + 5]);
        unsigned int a1 = cvtpk(p[base + 2], p[base + 3]);
        unsigned int b1 = cvtpk(p[base + 6], p[base + 7]);
        asm volatile("v_permlane32_swap_b32 %0, %1" : "+v"(a0), "+v"(b0));
        asm volatile("v_permlane32_swap_b32 %0, %1" : "+v"(a1), "+v"(b1));
        union { unsigned int w[4]; short8 v; } u;
        u.w[0] = a0; u.w[1] = a1; u.w[2] = b0; u.w[3] = b1;
        pa[kc] = u.v;
      }

      // ---- O += P V : B = V^T rows (d = nb*32 + l31), k-chunks of 16 ----
      const int dsw = (l31 & 7) << 4;
#pragma unroll
      for (int nb = 0; nb < 4; ++nb) {
        int rowb = (nb * 32 + l31) * (KT * 2);
        int sw = ((nb * 32 + l31) & 7) << 4;   // == dsw, kept explicit
        (void)dsw;
#pragma unroll
        for (int kc = 0; kc < 4; ++kc) {
          short8 vf = *(const short8*)(Vs + ((rowb + kc * 32 + h * 16) ^ sw));
          acc[nb] = __builtin_amdgcn_mfma_f32_32x32x16_bf16(pa[kc], vf, acc[nb], 0, 0, 0);
        }
      }
    }
  }

  // ---- epilogue: O / l ----
  float inv = 1.0f / l_run;   // per q = lane&31 (duplicated across halves)
  float* op = Og + ((long)b * SEQ + q0w) * strideS + (long)hh * HDIM;
#pragma unroll
  for (int i = 0; i < 16; ++i) {
    int qr = (i & 3) + 8 * (i >> 2) + 4 * h;
    float iv = __shfl(inv, qr, 64);
    long rb = (long)qr * strideS;
#pragma unroll
    for (int nb = 0; nb < 4; ++nb)
      op[rb + nb * 32 + l31] = acc[nb][i] * iv;
  }
}

extern "C" void kernel_launch(void* const* d_in, const int* in_sizes, int n_in,
                              void* d_out, int out_size, void* d_ws, size_t ws_size,
                              hipStream_t stream) {
  const float* Q = (const float*)d_in[0];
  const float* K = (const float*)d_in[1];
  const float* V = (const float*)d_in[2];
  const float* S = (const float*)d_in[3];
  float* O = (float*)d_out;
  dim3 grid(SEQ / QT, B_N * NH);
  dim3 block(256);
  fattn_kernel<<<grid, block, 0, stream>>>(Q, K, V, S, O);
}

// Round 3
// 205.796 us; speedup vs baseline: 3.7473x; 1.2916x over previous
//
#include <hip/hip_runtime.h>
#include <hip/hip_bf16.h>

typedef __attribute__((ext_vector_type(8))) short short8;
typedef __attribute__((ext_vector_type(16))) float f32x16;

#define B_N 4
#define SEQ 2048
#define NH 16
#define HDIM 128
#define QT 128      // q rows per block
#define QW 32       // q rows per wave
#define KT 64       // k tile
#define NT (SEQ / KT)            // 32 tiles
#define TILE_BYTES 32768         // 16KB K frags + 16KB V frags
#define WS_NEEDED ((size_t)B_N * NH * NT * TILE_BYTES)   // 67,108,864 B

static __device__ __forceinline__ unsigned short f2bf(float f) {
  union { __hip_bfloat16 h; unsigned short u; } cv;
  cv.h = __float2bfloat16(f);
  return cv.u;
}
static __device__ __forceinline__ unsigned int pack2(float a, float b) {
  return (unsigned int)f2bf(a) | ((unsigned int)f2bf(b) << 16);
}
static __device__ __forceinline__ unsigned int cvtpk(float lo, float hi) {
  unsigned int r;
  asm("v_cvt_pk_bf16_f32 %0, %1, %2" : "=v"(r) : "v"(lo), "v"(hi));
  return r;
}
static __device__ __forceinline__ void gload16(const void* g, void* l) {
  __builtin_amdgcn_global_load_lds(
      (const __attribute__((address_space(1))) unsigned int*)g,
      (__attribute__((address_space(3))) unsigned int*)l, 16, 0, 0);
}

// ============ pre-pass: K,V fp32 -> bf16 fragment-major tiles in ws ============
// Tile image (32 KB): [16 K-frags][16 V-frags], each frag 1 KB = 64 lanes x 16B.
// K frag f = pair*8+c: lane(hl,l31) <- K[pair*32+l31][c*16+hl*8 .. +8]
// V frag g = nb*4+kc : lane(hl,l31) <- V[kc*16+hl*8 .. +8][nb*32+l31] (k-major 8)
__global__ __launch_bounds__(256)
void prepass(const float* __restrict__ Kg, const float* __restrict__ Vg,
             char* __restrict__ ws)
{
  __shared__ __align__(16) char tile[16384];
  const int t  = blockIdx.x;        // 0..NT-1
  const int bh = blockIdx.y;        // 0..63
  const int b  = bh >> 4, hh = bh & (NH - 1);
  const int tid = threadIdx.x;
  const long strideS = (long)NH * HDIM;
  const float* kb = Kg + ((long)b * SEQ + t * KT) * strideS + (long)hh * HDIM;
  const float* vb = Vg + ((long)b * SEQ + t * KT) * strideS + (long)hh * HDIM;
  char* out = ws + ((long)bh * NT + t) * TILE_BYTES;

  // ---- K half ----
#pragma unroll
  for (int i = 0; i < 8; ++i) {
    int f4 = tid + i * 256;            // 0..2047
    int row = f4 >> 5, c4 = f4 & 31;   // row 0..63, float4-col 0..31
    float4 x = *(const float4*)(kb + (long)row * strideS + c4 * 4);
    uint2 w; w.x = pack2(x.x, x.y); w.y = pack2(x.z, x.w);
    int f    = (row >> 5) * 8 + (c4 >> 2);
    int lane = (((c4 >> 1) & 1) << 5) | (row & 31);
    *(uint2*)(tile + f * 1024 + lane * 16 + (c4 & 1) * 8) = w;
  }
  __syncthreads();
#pragma unroll
  for (int i = 0; i < 4; ++i)
    *(uint4*)(out + tid * 16 + i * 4096) = *(const uint4*)(tile + tid * 16 + i * 4096);
  __syncthreads();

  // ---- V half (transpose via 4x4 blocks) ----
#pragma unroll
  for (int i = 0; i < 2; ++i) {
    int blk = tid + i * 256;           // 0..511
    int d4 = blk & 31, k4 = blk >> 5;  // d-block 0..31, k-block 0..15
    const float* vp = vb + (long)(k4 * 4) * strideS + d4 * 4;
    float4 r0 = *(const float4*)vp;
    float4 r1 = *(const float4*)(vp + strideS);
    float4 r2 = *(const float4*)(vp + 2 * strideS);
    float4 r3 = *(const float4*)(vp + 3 * strideS);
    const float c0[4] = {r0.x, r0.y, r0.z, r0.w};
    const float c1[4] = {r1.x, r1.y, r1.z, r1.w};
    const float c2[4] = {r2.x, r2.y, r2.z, r2.w};
    const float c3[4] = {r3.x, r3.y, r3.z, r3.w};
    int g    = (d4 >> 3) * 4 + (k4 >> 2);
    int lhl  = ((k4 >> 1) & 1) << 5;
#pragma unroll
    for (int dd = 0; dd < 4; ++dd) {
      int lane = lhl | ((d4 & 7) * 4 + dd);
      uint2 w; w.x = pack2(c0[dd], c1[dd]); w.y = pack2(c2[dd], c3[dd]);
      *(uint2*)(tile + g * 1024 + lane * 16 + (k4 & 1) * 8) = w;
    }
  }
  __syncthreads();
#pragma unroll
  for (int i = 0; i < 4; ++i)
    *(uint4*)(out + 16384 + tid * 16 + i * 4096) =
        *(const uint4*)(tile + tid * 16 + i * 4096);
}

// ============ main attention kernel ============
__global__ __launch_bounds__(256, 2)
void fattn_main(const float* __restrict__ Qg, const float* __restrict__ Sg,
                const char* __restrict__ ws, float* __restrict__ Og)
{
  __shared__ __align__(16) char Buf[2][TILE_BYTES];   // 64 KB double buffer

  const int tid  = threadIdx.x;
  const int wv   = tid >> 6;
  const int lane = tid & 63;
  const int l31  = lane & 31;
  const int h    = lane >> 5;

  const int q0 = blockIdx.x * QT;
  const int bh = blockIdx.y;
  const int b  = bh >> 4;
  const int hh = bh & (NH - 1);

  const float slope = Sg[hh];
  const float scale = 0.08838834764831845f;   // 1/sqrt(128)
  const long strideS = (long)NH * HDIM;

  // Q fragments: B-operand (col = l31 = q, k = c*16 + h*8 + j), pre-scaled
  const int q0w  = q0 + wv * QW;
  const int qrow = q0w + l31;
  const float* qp = Qg + ((long)b * SEQ + qrow) * strideS + (long)hh * HDIM;
  short8 qf[8];
#pragma unroll
  for (int c = 0; c < 8; ++c) {
    const float* p = qp + c * 16 + h * 8;
    float4 x = *(const float4*)p;
    float4 y = *(const float4*)(p + 4);
    short8 f;
    f[0]=(short)f2bf(x.x*scale); f[1]=(short)f2bf(x.y*scale);
    f[2]=(short)f2bf(x.z*scale); f[3]=(short)f2bf(x.w*scale);
    f[4]=(short)f2bf(y.x*scale); f[5]=(short)f2bf(y.y*scale);
    f[6]=(short)f2bf(y.z*scale); f[7]=(short)f2bf(y.w*scale);
    qf[c] = f;
  }

  float m_run = -1e30f, l_run = 0.f;
  f32x16 acc[4];
#pragma unroll
  for (int nb = 0; nb < 4; ++nb)
#pragma unroll
    for (int i = 0; i < 16; ++i) acc[nb][i] = 0.f;

  const float q_f = (float)qrow;
  const int myend = (q0w + QW - 1) / KT;
  const int ntile = q0 / KT + 2;

  const char* wsbh = ws + (long)bh * NT * TILE_BYTES;

  // prologue: stage tile 0 into Buf[0]
#pragma unroll
  for (int i = 0; i < 8; ++i) {
    int seg = wv * 8 + i;
    gload16(wsbh + seg * 1024 + lane * 16, &Buf[0][seg * 1024]);
  }
  __syncthreads();

  for (int t = 0; t < ntile; ++t) {
    const char* cur = Buf[t & 1];
    if (t + 1 < ntile) {
      const char* src = wsbh + (long)(t + 1) * TILE_BYTES;
      char* nxt = Buf[(t + 1) & 1];
#pragma unroll
      for (int i = 0; i < 8; ++i) {
        int seg = wv * 8 + i;
        gload16(src + seg * 1024 + lane * 16, nxt + seg * 1024);
      }
    }

    if (t <= myend) {
      const char* Kb = cur;
      const char* Vb = cur + 16384;
      const int lb = lane * 16;

      // ---- S^T = K Q^T ----
      f32x16 s0, s1;
#pragma unroll
      for (int i = 0; i < 16; ++i) { s0[i] = 0.f; s1[i] = 0.f; }
#pragma unroll
      for (int c = 0; c < 8; ++c) {
        short8 ka = *(const short8*)(Kb + c * 1024 + lb);
        short8 k2 = *(const short8*)(Kb + (8 + c) * 1024 + lb);
        s0 = __builtin_amdgcn_mfma_f32_32x32x16_bf16(ka, qf[c], s0, 0, 0, 0);
        s1 = __builtin_amdgcn_mfma_f32_32x32x16_bf16(k2, qf[c], s1, 0, 0, 0);
      }

      // ---- ALiBi (+ causal on diagonal tile) ----
      const int k0 = t * KT;
      float p[32];
      float pm = -3.0e38f;
      const float kb0 = (float)(k0 + 4 * h) - q_f;
      if (t == myend) {
#pragma unroll
        for (int i = 0; i < 16; ++i) {
          float d0 = kb0 + (float)((i & 3) + 8 * (i >> 2));
          float v0 = __builtin_fmaf(slope, d0, s0[i]);
          v0 = (d0 > 0.f) ? -3.0e38f : v0;
          float d1 = d0 + 32.f;
          float v1 = __builtin_fmaf(slope, d1, s1[i]);
          v1 = (d1 > 0.f) ? -3.0e38f : v1;
          p[i] = v0; p[16 + i] = v1;
          pm = fmaxf(pm, fmaxf(v0, v1));
        }
      } else {
#pragma unroll
        for (int i = 0; i < 16; ++i) {
          float d0 = kb0 + (float)((i & 3) + 8 * (i >> 2));
          float v0 = __builtin_fmaf(slope, d0, s0[i]);
          float v1 = __builtin_fmaf(slope, d0 + 32.f, s1[i]);
          p[i] = v0; p[16 + i] = v1;
          pm = fmaxf(pm, fmaxf(v0, v1));
        }
      }
      pm = fmaxf(pm, __shfl_xor(pm, 32));

      // ---- online softmax with defer-rescale (THR=8) ----
      if (!__all(pm <= m_run + 8.0f)) {
        float M = fmaxf(m_run, pm);
        float alpha = __expf(m_run - M);
        m_run = M;
#pragma unroll
        for (int i = 0; i < 16; ++i) {
          int qr = (i & 3) + 8 * (i >> 2) + 4 * h;
          float al = __shfl(alpha, qr, 64);
          acc[0][i] *= al; acc[1][i] *= al; acc[2][i] *= al; acc[3][i] *= al;
        }
        l_run *= alpha;
      }
      float ps = 0.f;
#pragma unroll
      for (int i = 0; i < 32; ++i) {
        float e = __expf(p[i] - m_run);
        p[i] = e;
        ps += e;
      }
      ps += __shfl_xor(ps, 32);
      l_run += ps;

      // ---- P -> PV A-fragments (cvt_pk + permlane32_swap) ----
      short8 pa[4];
#pragma unroll
      for (int kc = 0; kc < 4; ++kc) {
        const int base = kc * 8;
        unsigned int a0 = cvtpk(p[base + 0], p[base + 1]);
        unsigned int b0 = cvtpk(p[base + 4], p[base + 5]);
        unsigned int a1 = cvtpk(p[base + 2], p[base + 3]);
        unsigned int b1 = cvtpk(p[base + 6], p[base + 7]);
        asm volatile("v_permlane32_swap_b32 %0, %1" : "+v"(a0), "+v"(b0));
        asm volatile("v_permlane32_swap_b32 %0, %1" : "+v"(a1), "+v"(b1));
        union { unsigned int w[4]; short8 v; } u;
        u.w[0] = a0; u.w[1] = a1; u.w[2] = b0; u.w[3] = b1;
        pa[kc] = u.v;
      }

      // ---- O += P V ----
#pragma unroll
      for (int nb = 0; nb < 4; ++nb)
#pragma unroll
        for (int kc = 0; kc < 4; ++kc) {
          short8 vf = *(const short8*)(Vb + (nb * 4 + kc) * 1024 + lb);
          acc[nb] = __builtin_amdgcn_mfma_f32_32x32x16_bf16(pa[kc], vf, acc[nb], 0, 0, 0);
        }
    }
    __syncthreads();   // drains vmcnt/lgkmcnt: next tile staged, cur free
  }

  // ---- epilogue ----
  float inv = 1.0f / l_run;
  float* op = Og + ((long)b * SEQ + q0w) * strideS + (long)hh * HDIM;
#pragma unroll
  for (int i = 0; i < 16; ++i) {
    int qr = (i & 3) + 8 * (i >> 2) + 4 * h;
    float iv = __shfl(inv, qr, 64);
    long rb = (long)qr * strideS;
#pragma unroll
    for (int nb = 0; nb < 4; ++nb)
      op[rb + nb * 32 + l31] = acc[nb][i] * iv;
  }
}

// ============ fallback (round-2 kernel, proven): used if ws too small ============
__global__ __launch_bounds__(256, 2)
void fattn_fb(const float* __restrict__ Qg, const float* __restrict__ Kg,
              const float* __restrict__ Vg, const float* __restrict__ Sg,
              float* __restrict__ Og)
{
  __shared__ __align__(16) char Ks[KT * HDIM * 2];
  __shared__ __align__(16) char Vs[HDIM * KT * 2];
  const int tid  = threadIdx.x;
  const int wv   = tid >> 6;
  const int lane = tid & 63;
  const int l31  = lane & 31;
  const int h    = lane >> 5;
  const int q0 = blockIdx.x * QT;
  const int bh = blockIdx.y;
  const int b  = bh >> 4;
  const int hh = bh & (NH - 1);
  const float slope = Sg[hh];
  const float scale = 0.08838834764831845f;
  const long strideS = (long)NH * HDIM;
  const int q0w  = q0 + wv * QW;
  const int qrow = q0w + l31;
  const float* qp = Qg + ((long)b * SEQ + qrow) * strideS + (long)hh * HDIM;
  short8 qf[8];
#pragma unroll
  for (int c = 0; c < 8; ++c) {
    const float* p = qp + c * 16 + h * 8;
    float4 x = *(const float4*)p;
    float4 y = *(const float4*)(p + 4);
    short8 f;
    f[0]=(short)f2bf(x.x*scale); f[1]=(short)f2bf(x.y*scale);
    f[2]=(short)f2bf(x.z*scale); f[3]=(short)f2bf(x.w*scale);
    f[4]=(short)f2bf(y.x*scale); f[5]=(short)f2bf(y.y*scale);
    f[6]=(short)f2bf(y.z*scale); f[7]=(short)f2bf(y.w*scale);
    qf[c] = f;
  }
  float m_run = -1e30f, l_run = 0.f;
  f32x16 acc[4];
#pragma unroll
  for (int nb = 0; nb < 4; ++nb)
#pragma unroll
    for (int i = 0; i < 16; ++i) acc[nb][i] = 0.f;
  const float* kb = Kg + (long)b * SEQ * strideS + (long)hh * HDIM;
  const float* vb = Vg + (long)b * SEQ * strideS + (long)hh * HDIM;
  const float q_f = (float)qrow;
  const int myend = (q0w + QW - 1) / KT;
  const int ntile = q0 / KT + 2;
  for (int t = 0; t < ntile; ++t) {
    const int k0 = t * KT;
    __syncthreads();
#pragma unroll
    for (int i = 0; i < 8; ++i) {
      int f4 = tid + i * 256;
      int row = f4 >> 5, c4 = f4 & 31;
      float4 x = *(const float4*)(kb + (long)(k0 + row) * strideS + c4 * 4);
      uint2 w; w.x = pack2(x.x, x.y); w.y = pack2(x.z, x.w);
      int byt = (row * 256 + c4 * 8) ^ ((row & 7) << 4);
      *(uint2*)(Ks + byt) = w;
    }
#pragma unroll
    for (int i = 0; i < 2; ++i) {
      int blk = tid + i * 256;
      int d4 = blk & 31, k4 = blk >> 5;
      const float* vp = vb + (long)(k0 + k4 * 4) * strideS + d4 * 4;
      float4 r0 = *(const float4*)vp;
      float4 r1 = *(const float4*)(vp + strideS);
      float4 r2 = *(const float4*)(vp + 2 * strideS);
      float4 r3 = *(const float4*)(vp + 3 * strideS);
      const float c0[4] = {r0.x, r0.y, r0.z, r0.w};
      const float c1[4] = {r1.x, r1.y, r1.z, r1.w};
      const float c2[4] = {r2.x, r2.y, r2.z, r2.w};
      const float c3[4] = {r3.x, r3.y, r3.z, r3.w};
#pragma unroll
      for (int dd = 0; dd < 4; ++dd) {
        int d = d4 * 4 + dd;
        uint2 w; w.x = pack2(c0[dd], c1[dd]); w.y = pack2(c2[dd], c3[dd]);
        int byt = (d * (KT * 2) + k4 * 8) ^ ((d & 7) << 4);
        *(uint2*)(Vs + byt) = w;
      }
    }
    __syncthreads();
    if (t <= myend) {
      f32x16 s0, s1;
#pragma unroll
      for (int i = 0; i < 16; ++i) { s0[i] = 0.f; s1[i] = 0.f; }
      const int swzk = (l31 & 7) << 4;
#pragma unroll
      for (int c = 0; c < 8; ++c) {
        int colb = c * 32 + h * 16;
        short8 ka = *(const short8*)(Ks + ((l31 * 256 + colb) ^ swzk));
        short8 kbf = *(const short8*)(Ks + (((l31 + 32) * 256 + colb) ^ swzk));
        s0 = __builtin_amdgcn_mfma_f32_32x32x16_bf16(ka, qf[c], s0, 0, 0, 0);
        s1 = __builtin_amdgcn_mfma_f32_32x32x16_bf16(kbf, qf[c], s1, 0, 0, 0);
      }
      float p[32];
      float pm = -1e30f;
#pragma unroll
      for (int i = 0; i < 16; ++i) {
        float kp0 = (float)(k0 + (i & 3) + 8 * (i >> 2) + 4 * h);
        float d0 = kp0 - q_f;
        float v0 = s0[i] + slope * d0;
        v0 = (d0 > 0.f) ? -1e30f : v0;
        p[i] = v0;
        float d1 = d0 + 32.f;
        float v1 = s1[i] + slope * d1;
        v1 = (d1 > 0.f) ? -1e30f : v1;
        p[16 + i] = v1;
        pm = fmaxf(pm, fmaxf(v0, v1));
      }
      pm = fmaxf(pm, __shfl_xor(pm, 32));
      if (!__all(pm <= m_run)) {
        float M = fmaxf(m_run, pm);
        float alpha = __expf(m_run - M);
        m_run = M;
#pragma unroll
        for (int i = 0; i < 16; ++i) {
          int qr = (i & 3) + 8 * (i >> 2) + 4 * h;
          float al = __shfl(alpha, qr, 64);
          acc[0][i] *= al; acc[1][i] *= al; acc[2][i] *= al; acc[3][i] *= al;
        }
        l_run *= alpha;
      }
      float ps = 0.f;
#pragma unroll
      for (int i = 0; i < 32; ++i) {
        float e = __expf(p[i] - m_run);
        p[i] = e;
        ps += e;
      }
      ps += __shfl_xor(ps, 32);
      l_run += ps;
      short8 pa[4];
#pragma unroll
      for (int kc = 0; kc < 4; ++kc) {
        const int base = kc * 8;
        unsigned int a0 = cvtpk(p[base + 0], p[base + 1]);
        unsigned int b0 = cvtpk(p[base + 4], p[base + 5]);
        unsigned int a1 = cvtpk(p[base + 2], p[base + 3]);
        unsigned int b1 = cvtpk(p[base + 6], p[base + 7]);
        asm volatile("v_permlane32_swap_b32 %0, %1" : "+v"(a0), "+v"(b0));
        asm volatile("v_permlane32_swap_b32 %0, %1" : "+v"(a1), "+v"(b1));
        union { unsigned int w[4]; short8 v; } u;
        u.w[0] = a0; u.w[1] = a1; u.w[2] = b0; u.w[3] = b1;
        pa[kc] = u.v;
      }
#pragma unroll
      for (int nb = 0; nb < 4; ++nb) {
        int rowb = (nb * 32 + l31) * (KT * 2);
        int sw = ((nb * 32 + l31) & 7) << 4;
#pragma unroll
        for (int kc = 0; kc < 4; ++kc) {
          short8 vf = *(const short8*)(Vs + ((rowb + kc * 32 + h * 16) ^ sw));
          acc[nb] = __builtin_amdgcn_mfma_f32_32x32x16_bf16(pa[kc], vf, acc[nb], 0, 0, 0);
        }
      }
    }
  }
  float inv = 1.0f / l_run;
  float* op = Og + ((long)b * SEQ + q0w) * strideS + (long)hh * HDIM;
#pragma unroll
  for (int i = 0; i < 16; ++i) {
    int qr = (i & 3) + 8 * (i >> 2) + 4 * h;
    float iv = __shfl(inv, qr, 64);
    long rb = (long)qr * strideS;
#pragma unroll
    for (int nb = 0; nb < 4; ++nb)
      op[rb + nb * 32 + l31] = acc[nb][i] * iv;
  }
}

extern "C" void kernel_launch(void* const* d_in, const int* in_sizes, int n_in,
                              void* d_out, int out_size, void* d_ws, size_t ws_size,
                              hipStream_t stream) {
  const float* Q = (const float*)d_in[0];
  const float* K = (const float*)d_in[1];
  const float* V = (const float*)d_in[2];
  const float* S = (const float*)d_in[3];
  float* O = (float*)d_out;
  if (ws_size >= WS_NEEDED) {
    prepass<<<dim3(NT, B_N * NH), 256, 0, stream>>>(K, V, (char*)d_ws);
    fattn_main<<<dim3(SEQ / QT, B_N * NH), 256, 0, stream>>>(Q, S, (const char*)d_ws, O);
  } else {
    fattn_fb<<<dim3(SEQ / QT, B_N * NH), 256, 0, stream>>>(Q, K, V, S, O);
  }
}